// Round 2
// baseline (1184.103 us; speedup 1.0000x reference)
//
#include <hip/hip_runtime.h>
#include <math.h>

typedef __attribute__((ext_vector_type(4))) float  f32x4;
typedef __attribute__((ext_vector_type(8))) __bf16 bf16x8;
typedef __attribute__((ext_vector_type(4))) __bf16 bf16x4;
typedef __attribute__((ext_vector_type(2))) __bf16 bf16x2;

#define B_   8
#define N_   256
#define C_   3072
#define H_   8
#define HD_  384
#define FF_  12288
#define EPS_ 1e-5f

// ---------------- conv QKV (one block per token) ----------------
__global__ __launch_bounds__(256) void k_conv_qkv(
    const float* __restrict__ x, const float* __restrict__ wq,
    const float* __restrict__ wk, const float* __restrict__ wv,
    __bf16* __restrict__ q, __bf16* __restrict__ kk, __bf16* __restrict__ vT)
{
    __shared__ float xs[3][34][34];
    __shared__ float wqs[81], wks[81], wvs[81];
    int tid = threadIdx.x;
    int token = blockIdx.x;
    int b = token >> 8, n = token & 255;

    for (int i = tid; i < 3 * 34 * 34; i += 256) ((float*)xs)[i] = 0.f;
    if (tid < 81) { wqs[tid] = wq[tid]; wks[tid] = wk[tid]; wvs[tid] = wv[tid]; }
    __syncthreads();
    const float* xp = x + (long)token * C_;
    for (int i = tid; i < C_; i += 256) {
        int ic = i >> 10, r = (i >> 5) & 31, c = i & 31;
        xs[ic][r + 1][c + 1] = xp[i];
    }
    __syncthreads();
    for (int i = tid; i < C_; i += 256) {
        int oc = i >> 10, r = (i >> 5) & 31, c = i & 31;
        float aq = 0.f, ak = 0.f, av = 0.f;
        #pragma unroll
        for (int ic = 0; ic < 3; ic++)
            #pragma unroll
            for (int dr = 0; dr < 3; dr++)
                #pragma unroll
                for (int dc = 0; dc < 3; dc++) {
                    float xv = xs[ic][r + dr][c + dc];
                    int wi = ((oc * 3 + ic) * 3 + dr) * 3 + dc;
                    aq = fmaf(wqs[wi], xv, aq);
                    ak = fmaf(wks[wi], xv, ak);
                    av = fmaf(wvs[wi], xv, av);
                }
        int h = i / HD_, d = i % HD_;
        long base = ((long)(b * H_ + h) * N_ + n) * HD_ + d;
        q[base]  = (__bf16)aq;
        kk[base] = (__bf16)ak;
        vT[((long)(b * H_ + h) * HD_ + d) * N_ + n] = (__bf16)av;
    }
}

// ---------------- transpose+cvt: w (K x Nc, f32) -> wT (Nc x K, bf16) ----------------
__global__ __launch_bounds__(256) void k_transpose(
    const float* __restrict__ w, __bf16* __restrict__ wT, int K, int Nc)
{
    __shared__ float t[64][65];
    int tid = threadIdx.x;
    long k0 = (long)blockIdx.y * 64, n0 = (long)blockIdx.x * 64;
    for (int i = tid; i < 4096; i += 256) {
        int r = i >> 6, c = i & 63;
        t[r][c] = w[(k0 + r) * Nc + n0 + c];
    }
    __syncthreads();
    for (int i = tid; i < 2048; i += 256) {
        int nr = i >> 5, k2 = (i & 31) * 2;
        bf16x2 pv;
        pv[0] = (__bf16)t[k2][nr];
        pv[1] = (__bf16)t[k2 + 1][nr];
        *(bf16x2*)&wT[(n0 + nr) * (long)K + k0 + k2] = pv;
    }
}

// ---------------- GEMM: C[MxN] = A[MxK] * B_nk[NxK]^T  (128x128 tile, bf16 MFMA) ----------------
#define EPI_SCALE_F32     0
#define EPI_BF16          1
#define EPI_BIAS_RES_F32  2
#define EPI_BIAS_GELU_B16 3

template<int EPI>
__global__ __launch_bounds__(256) void k_gemm(
    const __bf16* __restrict__ A, const __bf16* __restrict__ Bm,
    int lda, int ldb, int K,
    long sA1, long sA2, long sB1, long sB2, long sC1, long sC2,
    float scale, const float* __restrict__ bias, const float* __restrict__ res,
    void* __restrict__ Cp, int ldc)
{
    __shared__ alignas(16) __bf16 As[128 * 32];
    __shared__ alignas(16) __bf16 Bs[128 * 32];
    int tid = threadIdx.x;
    int z = blockIdx.z;
    const __bf16* Ab = A + (z & 7) * sA1 + (z >> 3) * sA2 + (long)blockIdx.y * 128 * lda;
    const __bf16* Bb = Bm + (z & 7) * sB1 + (z >> 3) * sB2 + (long)blockIdx.x * 128 * ldb;
    long coff = (z & 7) * sC1 + (z >> 3) * sC2;
    int lane = tid & 63, wid = tid >> 6;
    int wm = (wid >> 1) * 64, wn = (wid & 1) * 64;
    int lr = lane & 15, lk = lane >> 4;
    int srow = tid >> 2, su = tid & 3;

    f32x4 acc[4][4] = {};

    for (int k0 = 0; k0 < K; k0 += 32) {
        __syncthreads();
        #pragma unroll
        for (int i = 0; i < 2; i++) {
            int row = srow + i * 64;
            *(uint4*)&As[row * 32 + su * 8] = *(const uint4*)(Ab + (long)row * lda + k0 + su * 8);
            *(uint4*)&Bs[row * 32 + su * 8] = *(const uint4*)(Bb + (long)row * ldb + k0 + su * 8);
        }
        __syncthreads();
        bf16x8 af[4], bfr[4];
        #pragma unroll
        for (int mi = 0; mi < 4; mi++) af[mi]  = *(const bf16x8*)&As[(wm + mi * 16 + lr) * 32 + lk * 8];
        #pragma unroll
        for (int ni = 0; ni < 4; ni++) bfr[ni] = *(const bf16x8*)&Bs[(wn + ni * 16 + lr) * 32 + lk * 8];
        #pragma unroll
        for (int mi = 0; mi < 4; mi++)
            #pragma unroll
            for (int ni = 0; ni < 4; ni++)
                acc[mi][ni] = __builtin_amdgcn_mfma_f32_16x16x32_bf16(af[mi], bfr[ni], acc[mi][ni], 0, 0, 0);
    }

    int row0 = blockIdx.y * 128 + wm + lk * 4;
    int col0 = blockIdx.x * 128 + wn + lr;
    #pragma unroll
    for (int mi = 0; mi < 4; mi++)
        #pragma unroll
        for (int ni = 0; ni < 4; ni++)
            #pragma unroll
            for (int r = 0; r < 4; r++) {
                int row = row0 + mi * 16 + r;
                int col = col0 + ni * 16;
                float v = acc[mi][ni][r];
                if constexpr (EPI == EPI_SCALE_F32) {
                    ((float*)Cp)[coff + (long)row * ldc + col] = v * scale;
                } else if constexpr (EPI == EPI_BF16) {
                    ((__bf16*)Cp)[coff + (long)row * ldc + col] = (__bf16)v;
                } else if constexpr (EPI == EPI_BIAS_RES_F32) {
                    ((float*)Cp)[coff + (long)row * ldc + col] = v + bias[col] + res[(long)row * ldc + col];
                } else {
                    float tv = v + bias[col];
                    float g = 0.5f * tv * (1.f + erff(tv * 0.70710678118654752f));
                    ((__bf16*)Cp)[coff + (long)row * ldc + col] = (__bf16)g;
                }
            }
}

// ---------------- softmax over rows of 256 (one wave per row) ----------------
__global__ __launch_bounds__(256) void k_softmax(float* __restrict__ S)
{
    int row = blockIdx.x * 4 + (threadIdx.x >> 6);
    int lane = threadIdx.x & 63;
    float* p = S + (long)row * 256 + lane * 4;
    f32x4 v = *(f32x4*)p;
    float mx = fmaxf(fmaxf(v[0], v[1]), fmaxf(v[2], v[3]));
    #pragma unroll
    for (int o = 32; o > 0; o >>= 1) mx = fmaxf(mx, __shfl_xor(mx, o, 64));
    v[0] = __expf(v[0] - mx); v[1] = __expf(v[1] - mx);
    v[2] = __expf(v[2] - mx); v[3] = __expf(v[3] - mx);
    float s = v[0] + v[1] + v[2] + v[3];
    #pragma unroll
    for (int o = 32; o > 0; o >>= 1) s += __shfl_xor(s, o, 64);
    float inv = 1.f / s;
    v *= inv;
    *(f32x4*)p = v;
}

// ---------------- head remix (1x1 conv over heads) + BatchNorm(eval) ----------------
__global__ __launch_bounds__(256) void k_headmix(
    const float* __restrict__ S, __bf16* __restrict__ attn2,
    const float* __restrict__ W, const float* __restrict__ rb,
    const float* __restrict__ bg, const float* __restrict__ bb,
    const float* __restrict__ bm, const float* __restrict__ bv)
{
    long idx = (long)blockIdx.x * 256 + threadIdx.x;   // over B*N*N
    int b = (int)(idx >> 16);
    int nm = (int)(idx & 65535);
    const float* sp = S + (long)b * (H_ * 65536) + nm;
    float a[8];
    #pragma unroll
    for (int h = 0; h < 8; h++) a[h] = sp[(long)h * 65536];
    __bf16* op = attn2 + (long)b * (H_ * 65536) + nm;
    #pragma unroll
    for (int o = 0; o < 8; o++) {
        float acc = rb[o];
        #pragma unroll
        for (int h = 0; h < 8; h++) acc = fmaf(W[o * 8 + h], a[h], acc);
        float inv = rsqrtf(bv[o] + EPS_);
        float outv = (acc - bm[o]) * (bg[o] * inv) + bb[o];
        op[(long)o * 65536] = (__bf16)outv;
    }
}

// ---------------- LayerNorm over (N,C) per sample: partial sums then apply ----------------
__global__ __launch_bounds__(256) void k_ln_part(const float* __restrict__ t, float* __restrict__ part)
{
    int bid = blockIdx.x;                    // 8 samples * 32 chunks
    const f32x4* pb = (const f32x4*)(t + (long)bid * 24576);
    float sum = 0.f, ss = 0.f;
    for (int i = threadIdx.x; i < 6144; i += 256) {
        f32x4 v = pb[i];
        sum += v[0] + v[1] + v[2] + v[3];
        ss  += v[0] * v[0] + v[1] * v[1] + v[2] * v[2] + v[3] * v[3];
    }
    #pragma unroll
    for (int o = 32; o > 0; o >>= 1) { sum += __shfl_xor(sum, o, 64); ss += __shfl_xor(ss, o, 64); }
    __shared__ float red[8];
    int wid = threadIdx.x >> 6, lane = threadIdx.x & 63;
    if (lane == 0) { red[wid * 2] = sum; red[wid * 2 + 1] = ss; }
    __syncthreads();
    if (threadIdx.x == 0) {
        part[bid * 2]     = red[0] + red[2] + red[4] + red[6];
        part[bid * 2 + 1] = red[1] + red[3] + red[5] + red[7];
    }
}

__global__ __launch_bounds__(256) void k_ln_apply(
    const float* __restrict__ t, const float* __restrict__ part,
    const float* __restrict__ gamma, const float* __restrict__ beta,
    float* __restrict__ yo, __bf16* __restrict__ yb)
{
    int bid = blockIdx.x;
    int s = bid >> 5, c = bid & 31;
    float sum = 0.f, ss = 0.f;
    #pragma unroll
    for (int i = 0; i < 32; i++) { sum += part[(s * 32 + i) * 2]; ss += part[(s * 32 + i) * 2 + 1]; }
    const float rn = 1.f / 786432.f;
    float mean = sum * rn;
    float var = ss * rn - mean * mean;
    float inv = rsqrtf(var + EPS_);
    long off = (long)bid * 6144;     // in f32x4 units
    long goff = (long)c * 6144;
    const f32x4* tp = (const f32x4*)t + off;
    const f32x4* gp = (const f32x4*)gamma + goff;
    const f32x4* bp = (const f32x4*)beta + goff;
    f32x4* yp = (f32x4*)yo + off;
    for (int i = threadIdx.x; i < 6144; i += 256) {
        f32x4 v = tp[i], g = gp[i], bt = bp[i];
        f32x4 o = (v - mean) * inv * g + bt;
        yp[i] = o;
        if (yb) {
            bf16x4 ob;
            ob[0] = (__bf16)o[0]; ob[1] = (__bf16)o[1]; ob[2] = (__bf16)o[2]; ob[3] = (__bf16)o[3];
            ((bf16x4*)yb)[off + i] = ob;
        }
    }
}

// ---------------- launch ----------------
extern "C" void kernel_launch(void* const* d_in, const int* in_sizes, int n_in,
                              void* d_out, int out_size, void* d_ws, size_t ws_size,
                              hipStream_t stream)
{
    const float* x  = (const float*)d_in[0];
    const float* wq = (const float*)d_in[1];
    const float* wk = (const float*)d_in[2];
    const float* wv = (const float*)d_in[3];
    const float* rw = (const float*)d_in[4];
    const float* rb = (const float*)d_in[5];
    const float* bg = (const float*)d_in[6];
    const float* bb = (const float*)d_in[7];
    const float* bm = (const float*)d_in[8];
    const float* bv = (const float*)d_in[9];
    const float* pw = (const float*)d_in[10];
    const float* pb = (const float*)d_in[11];
    const float* lg = (const float*)d_in[12];
    const float* lb = (const float*)d_in[13];
    const float* w1 = (const float*)d_in[14];
    const float* b1 = (const float*)d_in[15];
    const float* w2 = (const float*)d_in[16];
    const float* b2 = (const float*)d_in[17];
    float* out = (float*)d_out;

    char* ws = (char*)d_ws;
    __bf16* q    = (__bf16*)(ws + 0);            // 12.58 MB; reused as attn_out
    __bf16* kbuf = (__bf16*)(ws + 12582912);
    __bf16* vT   = (__bf16*)(ws + 25165824);
    float*  S    = (float*) (ws + 37748736);     // 16.78 MB
    __bf16* a2   = (__bf16*)(ws + 54525952);     // 8.39 MB
    __bf16* hbuf = (__bf16*)(ws + 12582912);     // alias kbuf..a2 (50.33 MB), dead by then
    float*  t1   = (float*) (ws + 62914560);     // 25.17 MB (also t2)
    float*  y    = (float*) (ws + 88080384);     // 25.17 MB
    __bf16* ybf  = (__bf16*)(ws + 113246208);    // 12.58 MB
    __bf16* wT   = (__bf16*)(ws + 125829120);    // 75.50 MB (proj/w1/w2 transposed, sequential reuse)
    float*  part = (float*) (ws + 201326592);    // 2 KB
    __bf16* aout = q;

    const float scale = 0.051031036307982884f;   // 384^-0.5

    k_conv_qkv<<<2048, 256, 0, stream>>>(x, wq, wk, wv, q, kbuf, vT);

    // S = softmax-input: q @ k^T * scale   (batched over B*H)
    k_gemm<EPI_SCALE_F32><<<dim3(2, 2, 64), 256, 0, stream>>>(
        q, kbuf, 384, 384, 384,
        98304, 786432, 98304, 786432, 65536, 524288,
        scale, nullptr, nullptr, S, 256);
    k_softmax<<<4096, 256, 0, stream>>>(S);
    k_headmix<<<2048, 256, 0, stream>>>(S, a2, rw, rb, bg, bb, bm, bv);

    // attn_out = attn2 @ v   (batched, scattered into (B,N,C))
    k_gemm<EPI_BF16><<<dim3(3, 2, 64), 256, 0, stream>>>(
        a2, vT, 256, 256, 256,
        65536, 524288, 98304, 786432, 384, 786432,
        1.f, nullptr, nullptr, aout, 3072);

    // t1 = x + attn_out @ proj_w + proj_b
    k_transpose<<<dim3(48, 48), 256, 0, stream>>>(pw, wT, 3072, 3072);
    k_gemm<EPI_BIAS_RES_F32><<<dim3(24, 16, 1), 256, 0, stream>>>(
        aout, wT, 3072, 3072, 3072,
        0, 0, 0, 0, 0, 0,
        1.f, pb, x, t1, 3072);

    // y = LN(t1)
    k_ln_part<<<256, 256, 0, stream>>>(t1, part);
    k_ln_apply<<<256, 256, 0, stream>>>(t1, part, lg, lb, y, ybf);

    // h = gelu(y @ ff_w1 + b1)
    k_transpose<<<dim3(192, 48), 256, 0, stream>>>(w1, wT, 3072, 12288);
    k_gemm<EPI_BIAS_GELU_B16><<<dim3(96, 16, 1), 256, 0, stream>>>(
        ybf, wT, 3072, 3072, 3072,
        0, 0, 0, 0, 0, 0,
        1.f, b1, nullptr, hbuf, 12288);

    // t2 = y + h @ ff_w2 + b2   (reuse t1 buffer)
    k_transpose<<<dim3(48, 192), 256, 0, stream>>>(w2, wT, 12288, 3072);
    k_gemm<EPI_BIAS_RES_F32><<<dim3(24, 16, 1), 256, 0, stream>>>(
        hbuf, wT, 12288, 12288, 12288,
        0, 0, 0, 0, 0, 0,
        1.f, b2, y, t1, 3072);

    // out = LN(t2)
    k_ln_part<<<256, 256, 0, stream>>>(t1, part);
    k_ln_apply<<<256, 256, 0, stream>>>(t1, part, lg, lb, out, nullptr);
}

// Round 4
// 1180.893 us; speedup vs baseline: 1.0027x; 1.0027x over previous
//
#include <hip/hip_runtime.h>
#include <math.h>

typedef __attribute__((ext_vector_type(4))) float  f32x4;
typedef __attribute__((ext_vector_type(8))) __bf16 bf16x8;
typedef __attribute__((ext_vector_type(4))) __bf16 bf16x4;
typedef __attribute__((ext_vector_type(2))) __bf16 bf16x2;

#define B_   8
#define N_   256
#define C_   3072
#define H_   8
#define HD_  384
#define FF_  12288
#define EPS_ 1e-5f

__device__ __forceinline__ void gload_lds16(const void* g, void* l) {
    __builtin_amdgcn_global_load_lds(
        (const __attribute__((address_space(1))) unsigned int*)g,
        (__attribute__((address_space(3))) unsigned int*)l, 16, 0, 0);
}

// ---------------- conv QKV (one block per token) ----------------
__global__ __launch_bounds__(256) void k_conv_qkv(
    const float* __restrict__ x, const float* __restrict__ wq,
    const float* __restrict__ wk, const float* __restrict__ wv,
    __bf16* __restrict__ q, __bf16* __restrict__ kk, __bf16* __restrict__ vT)
{
    __shared__ float xs[3][34][34];
    __shared__ float wqs[81], wks[81], wvs[81];
    int tid = threadIdx.x;
    int token = blockIdx.x;
    int b = token >> 8, n = token & 255;

    for (int i = tid; i < 3 * 34 * 34; i += 256) ((float*)xs)[i] = 0.f;
    if (tid < 81) { wqs[tid] = wq[tid]; wks[tid] = wk[tid]; wvs[tid] = wv[tid]; }
    __syncthreads();
    const float* xp = x + (long)token * C_;
    for (int i = tid; i < C_; i += 256) {
        int ic = i >> 10, r = (i >> 5) & 31, c = i & 31;
        xs[ic][r + 1][c + 1] = xp[i];
    }
    __syncthreads();
    for (int i = tid; i < C_; i += 256) {
        int oc = i >> 10, r = (i >> 5) & 31, c = i & 31;
        float aq = 0.f, ak = 0.f, av = 0.f;
        #pragma unroll
        for (int ic = 0; ic < 3; ic++)
            #pragma unroll
            for (int dr = 0; dr < 3; dr++)
                #pragma unroll
                for (int dc = 0; dc < 3; dc++) {
                    float xv = xs[ic][r + dr][c + dc];
                    int wi = ((oc * 3 + ic) * 3 + dr) * 3 + dc;
                    aq = fmaf(wqs[wi], xv, aq);
                    ak = fmaf(wks[wi], xv, ak);
                    av = fmaf(wvs[wi], xv, av);
                }
        int h = i / HD_, d = i % HD_;
        long base = ((long)(b * H_ + h) * N_ + n) * HD_ + d;
        q[base]  = (__bf16)aq;
        kk[base] = (__bf16)ak;
        vT[((long)(b * H_ + h) * HD_ + d) * N_ + n] = (__bf16)av;
    }
}

// ---------------- transpose+cvt: w (K x Nc, f32) -> wT (Nc x K, bf16) ----------------
__global__ __launch_bounds__(256) void k_transpose(
    const float* __restrict__ w, __bf16* __restrict__ wT, int K, int Nc)
{
    __shared__ float t[64][65];
    int tid = threadIdx.x;
    long k0 = (long)blockIdx.y * 64, n0 = (long)blockIdx.x * 64;
    for (int i = tid; i < 4096; i += 256) {
        int r = i >> 6, c = i & 63;
        t[r][c] = w[(k0 + r) * Nc + n0 + c];
    }
    __syncthreads();
    for (int i = tid; i < 2048; i += 256) {
        int nr = i >> 5, k2 = (i & 31) * 2;
        bf16x2 pv;
        pv[0] = (__bf16)t[k2][nr];
        pv[1] = (__bf16)t[k2 + 1][nr];
        *(bf16x2*)&wT[(n0 + nr) * (long)K + k0 + k2] = pv;
    }
}

// ---------------- GEMM: C[MxN] = A[MxK] * B_nk[NxK]^T  (128x128 tile, bf16 MFMA,
//                  global_load_lds dwordx4 staging) ----------------
#define EPI_SCALE_F32     0
#define EPI_BF16          1
#define EPI_BIAS_RES_F32  2
#define EPI_BIAS_GELU_B16 3

template<int EPI>
__global__ __launch_bounds__(256) void k_gemm(
    const __bf16* __restrict__ A, const __bf16* __restrict__ Bm,
    int lda, int ldb, int K,
    long sA1, long sA2, long sB1, long sB2, long sC1, long sC2,
    float scale, const float* __restrict__ bias, const float* __restrict__ res,
    void* __restrict__ Cp, int ldc)
{
    __shared__ alignas(16) __bf16 As[128 * 32];
    __shared__ alignas(16) __bf16 Bs[128 * 32];
    int tid = threadIdx.x;
    int z = blockIdx.z;
    const __bf16* Ab = A + (z & 7) * sA1 + (z >> 3) * sA2 + (long)blockIdx.y * 128 * lda;
    const __bf16* Bb = Bm + (z & 7) * sB1 + (z >> 3) * sB2 + (long)blockIdx.x * 128 * ldb;
    long coff = (z & 7) * sC1 + (z >> 3) * sC2;
    int lane = tid & 63, wid = tid >> 6;
    int wm = (wid >> 1) * 64, wn = (wid & 1) * 64;
    int lr = lane & 15, lk = lane >> 4;
    int srow = tid >> 2, su = tid & 3;      // srow = wid*16 + (lane>>2)

    // wave-uniform LDS bases: wave w stages rows [w*16, w*16+16) of each 64-row half;
    // lane l lands at base + l*16 B (linear, matches row*64B + (l&3)*16B)
    __bf16* lA0 = As + (wid * 16) * 32;
    __bf16* lB0 = Bs + (wid * 16) * 32;

    f32x4 acc[4][4] = {};

    for (int k0 = 0; k0 < K; k0 += 32) {
        __syncthreads();
        #pragma unroll
        for (int i = 0; i < 2; i++) {
            int row = srow + i * 64;
            gload_lds16(Ab + (long)row * lda + k0 + su * 8, lA0 + i * 64 * 32);
            gload_lds16(Bb + (long)row * ldb + k0 + su * 8, lB0 + i * 64 * 32);
        }
        __syncthreads();   // drains vmcnt(0): staged data visible
        bf16x8 af[4], bfr[4];
        #pragma unroll
        for (int mi = 0; mi < 4; mi++) af[mi]  = *(const bf16x8*)&As[(wm + mi * 16 + lr) * 32 + lk * 8];
        #pragma unroll
        for (int ni = 0; ni < 4; ni++) bfr[ni] = *(const bf16x8*)&Bs[(wn + ni * 16 + lr) * 32 + lk * 8];
        #pragma unroll
        for (int mi = 0; mi < 4; mi++)
            #pragma unroll
            for (int ni = 0; ni < 4; ni++)
                acc[mi][ni] = __builtin_amdgcn_mfma_f32_16x16x32_bf16(af[mi], bfr[ni], acc[mi][ni], 0, 0, 0);
    }

    int row0 = blockIdx.y * 128 + wm + lk * 4;
    int col0 = blockIdx.x * 128 + wn + lr;
    #pragma unroll
    for (int mi = 0; mi < 4; mi++)
        #pragma unroll
        for (int ni = 0; ni < 4; ni++)
            #pragma unroll
            for (int r = 0; r < 4; r++) {
                int row = row0 + mi * 16 + r;
                int col = col0 + ni * 16;
                float v = acc[mi][ni][r];
                if constexpr (EPI == EPI_SCALE_F32) {
                    ((float*)Cp)[coff + (long)row * ldc + col] = v * scale;
                } else if constexpr (EPI == EPI_BF16) {
                    ((__bf16*)Cp)[coff + (long)row * ldc + col] = (__bf16)v;
                } else if constexpr (EPI == EPI_BIAS_RES_F32) {
                    ((float*)Cp)[coff + (long)row * ldc + col] = v + bias[col] + res[(long)row * ldc + col];
                } else {
                    float tv = v + bias[col];
                    float g = 0.5f * tv * (1.f + erff(tv * 0.70710678118654752f));
                    ((__bf16*)Cp)[coff + (long)row * ldc + col] = (__bf16)g;
                }
            }
}

// ---------------- softmax over rows of 256 (one wave per row) ----------------
__global__ __launch_bounds__(256) void k_softmax(float* __restrict__ S)
{
    int row = blockIdx.x * 4 + (threadIdx.x >> 6);
    int lane = threadIdx.x & 63;
    float* p = S + (long)row * 256 + lane * 4;
    f32x4 v = *(f32x4*)p;
    float mx = fmaxf(fmaxf(v[0], v[1]), fmaxf(v[2], v[3]));
    #pragma unroll
    for (int o = 32; o > 0; o >>= 1) mx = fmaxf(mx, __shfl_xor(mx, o, 64));
    v[0] = __expf(v[0] - mx); v[1] = __expf(v[1] - mx);
    v[2] = __expf(v[2] - mx); v[3] = __expf(v[3] - mx);
    float s = v[0] + v[1] + v[2] + v[3];
    #pragma unroll
    for (int o = 32; o > 0; o >>= 1) s += __shfl_xor(s, o, 64);
    float inv = 1.f / s;
    v *= inv;
    *(f32x4*)p = v;
}

// ---------------- head remix (1x1 conv over heads) + BatchNorm(eval) ----------------
__global__ __launch_bounds__(256) void k_headmix(
    const float* __restrict__ S, __bf16* __restrict__ attn2,
    const float* __restrict__ W, const float* __restrict__ rb,
    const float* __restrict__ bg, const float* __restrict__ bb,
    const float* __restrict__ bm, const float* __restrict__ bv)
{
    long idx = (long)blockIdx.x * 256 + threadIdx.x;   // over B*N*N
    int b = (int)(idx >> 16);
    int nm = (int)(idx & 65535);
    const float* sp = S + (long)b * (H_ * 65536) + nm;
    float a[8];
    #pragma unroll
    for (int h = 0; h < 8; h++) a[h] = sp[(long)h * 65536];
    __bf16* op = attn2 + (long)b * (H_ * 65536) + nm;
    #pragma unroll
    for (int o = 0; o < 8; o++) {
        float acc = rb[o];
        #pragma unroll
        for (int h = 0; h < 8; h++) acc = fmaf(W[o * 8 + h], a[h], acc);
        float inv = rsqrtf(bv[o] + EPS_);
        float outv = (acc - bm[o]) * (bg[o] * inv) + bb[o];
        op[(long)o * 65536] = (__bf16)outv;
    }
}

// ---------------- LayerNorm over (N,C) per sample: partial sums then apply ----------------
__global__ __launch_bounds__(256) void k_ln_part(const float* __restrict__ t, float* __restrict__ part)
{
    int bid = blockIdx.x;                    // 8 samples * 32 chunks
    const f32x4* pb = (const f32x4*)(t + (long)bid * 24576);
    float sum = 0.f, ss = 0.f;
    for (int i = threadIdx.x; i < 6144; i += 256) {
        f32x4 v = pb[i];
        sum += v[0] + v[1] + v[2] + v[3];
        ss  += v[0] * v[0] + v[1] * v[1] + v[2] * v[2] + v[3] * v[3];
    }
    #pragma unroll
    for (int o = 32; o > 0; o >>= 1) { sum += __shfl_xor(sum, o, 64); ss += __shfl_xor(ss, o, 64); }
    __shared__ float red[8];
    int wid = threadIdx.x >> 6, lane = threadIdx.x & 63;
    if (lane == 0) { red[wid * 2] = sum; red[wid * 2 + 1] = ss; }
    __syncthreads();
    if (threadIdx.x == 0) {
        part[bid * 2]     = red[0] + red[2] + red[4] + red[6];
        part[bid * 2 + 1] = red[1] + red[3] + red[5] + red[7];
    }
}

__global__ __launch_bounds__(256) void k_ln_apply(
    const float* __restrict__ t, const float* __restrict__ part,
    const float* __restrict__ gamma, const float* __restrict__ beta,
    float* __restrict__ yo, __bf16* __restrict__ yb)
{
    int bid = blockIdx.x;
    int s = bid >> 5, c = bid & 31;
    float sum = 0.f, ss = 0.f;
    #pragma unroll
    for (int i = 0; i < 32; i++) { sum += part[(s * 32 + i) * 2]; ss += part[(s * 32 + i) * 2 + 1]; }
    const float rn = 1.f / 786432.f;
    float mean = sum * rn;
    float var = ss * rn - mean * mean;
    float inv = rsqrtf(var + EPS_);
    long off = (long)bid * 6144;     // in f32x4 units
    long goff = (long)c * 6144;
    const f32x4* tp = (const f32x4*)t + off;
    const f32x4* gp = (const f32x4*)gamma + goff;
    const f32x4* bp = (const f32x4*)beta + goff;
    f32x4* yp = (f32x4*)yo + off;
    for (int i = threadIdx.x; i < 6144; i += 256) {
        f32x4 v = tp[i], g = gp[i], bt = bp[i];
        f32x4 o = (v - mean) * inv * g + bt;
        yp[i] = o;
        if (yb) {
            bf16x4 ob;
            ob[0] = (__bf16)o[0]; ob[1] = (__bf16)o[1]; ob[2] = (__bf16)o[2]; ob[3] = (__bf16)o[3];
            ((bf16x4*)yb)[off + i] = ob;
        }
    }
}

// ---------------- launch ----------------
extern "C" void kernel_launch(void* const* d_in, const int* in_sizes, int n_in,
                              void* d_out, int out_size, void* d_ws, size_t ws_size,
                              hipStream_t stream)
{
    const float* x  = (const float*)d_in[0];
    const float* wq = (const float*)d_in[1];
    const float* wk = (const float*)d_in[2];
    const float* wv = (const float*)d_in[3];
    const float* rw = (const float*)d_in[4];
    const float* rb = (const float*)d_in[5];
    const float* bg = (const float*)d_in[6];
    const float* bb = (const float*)d_in[7];
    const float* bm = (const float*)d_in[8];
    const float* bv = (const float*)d_in[9];
    const float* pw = (const float*)d_in[10];
    const float* pb = (const float*)d_in[11];
    const float* lg = (const float*)d_in[12];
    const float* lb = (const float*)d_in[13];
    const float* w1 = (const float*)d_in[14];
    const float* b1 = (const float*)d_in[15];
    const float* w2 = (const float*)d_in[16];
    const float* b2 = (const float*)d_in[17];
    float* out = (float*)d_out;

    char* ws = (char*)d_ws;
    __bf16* q    = (__bf16*)(ws + 0);            // 12.58 MB; reused as attn_out
    __bf16* kbuf = (__bf16*)(ws + 12582912);
    __bf16* vT   = (__bf16*)(ws + 25165824);
    float*  S    = (float*) (ws + 37748736);     // 16.78 MB
    __bf16* a2   = (__bf16*)(ws + 54525952);     // 8.39 MB
    __bf16* hbuf = (__bf16*)(ws + 12582912);     // alias kbuf..a2 (50.33 MB), dead by then
    float*  t1   = (float*) (ws + 62914560);     // 25.17 MB (also t2)
    float*  y    = (float*) (ws + 88080384);     // 25.17 MB
    __bf16* ybf  = (__bf16*)(ws + 113246208);    // 12.58 MB
    __bf16* wT   = (__bf16*)(ws + 125829120);    // 75.50 MB (proj/w1/w2 transposed, sequential reuse)
    float*  part = (float*) (ws + 201326592);    // 2 KB
    __bf16* aout = q;

    const float scale = 0.051031036307982884f;   // 384^-0.5

    k_conv_qkv<<<2048, 256, 0, stream>>>(x, wq, wk, wv, q, kbuf, vT);

    // S = softmax-input: q @ k^T * scale   (batched over B*H)
    k_gemm<EPI_SCALE_F32><<<dim3(2, 2, 64), 256, 0, stream>>>(
        q, kbuf, 384, 384, 384,
        98304, 786432, 98304, 786432, 65536, 524288,
        scale, nullptr, nullptr, S, 256);
    k_softmax<<<4096, 256, 0, stream>>>(S);
    k_headmix<<<2048, 256, 0, stream>>>(S, a2, rw, rb, bg, bb, bm, bv);

    // attn_out = attn2 @ v   (batched, scattered into (B,N,C))
    k_gemm<EPI_BF16><<<dim3(3, 2, 64), 256, 0, stream>>>(
        a2, vT, 256, 256, 256,
        65536, 524288, 98304, 786432, 384, 786432,
        1.f, nullptr, nullptr, aout, 3072);

    // t1 = x + attn_out @ proj_w + proj_b
    k_transpose<<<dim3(48, 48), 256, 0, stream>>>(pw, wT, 3072, 3072);
    k_gemm<EPI_BIAS_RES_F32><<<dim3(24, 16, 1), 256, 0, stream>>>(
        aout, wT, 3072, 3072, 3072,
        0, 0, 0, 0, 0, 0,
        1.f, pb, x, t1, 3072);

    // y = LN(t1)
    k_ln_part<<<256, 256, 0, stream>>>(t1, part);
    k_ln_apply<<<256, 256, 0, stream>>>(t1, part, lg, lb, y, ybf);

    // h = gelu(y @ ff_w1 + b1)
    k_transpose<<<dim3(192, 48), 256, 0, stream>>>(w1, wT, 3072, 12288);
    k_gemm<EPI_BIAS_GELU_B16><<<dim3(96, 16, 1), 256, 0, stream>>>(
        ybf, wT, 3072, 3072, 3072,
        0, 0, 0, 0, 0, 0,
        1.f, b1, nullptr, hbuf, 12288);

    // t2 = y + h @ ff_w2 + b2   (reuse t1 buffer)
    k_transpose<<<dim3(48, 192), 256, 0, stream>>>(w2, wT, 12288, 3072);
    k_gemm<EPI_BIAS_RES_F32><<<dim3(24, 16, 1), 256, 0, stream>>>(
        hbuf, wT, 12288, 12288, 12288,
        0, 0, 0, 0, 0, 0,
        1.f, b2, y, t1, 3072);

    // out = LN(t2)
    k_ln_part<<<256, 256, 0, stream>>>(t1, part);
    k_ln_apply<<<256, 256, 0, stream>>>(t1, part, lg, lb, out, nullptr);
}